// Round 1
// baseline (60.544 us; speedup 1.0000x reference)
//
#include <hip/hip_runtime.h>
#include <math.h>

// Problem constants (from reference): B=4, R=4096, S=48, C=32
#define NRAYS   (4 * 4096)   // 16384
#define S_SAMP  48
#define C_CH    32
#define SM1     (S_SAMP - 1) // 47
#define LPR     16           // lanes per ray (each lane owns 2 channels)

// Output flat layout (floats):
//   composite_rgb   [NRAYS * C_CH]  at 0
//   composite_depth [NRAYS]         at NRAYS*C_CH
//   weights         [NRAYS * SM1]   at NRAYS*C_CH + NRAYS
//   weight_total    [NRAYS]         at NRAYS*C_CH + NRAYS + NRAYS*SM1
#define OFF_RGB   0
#define OFF_DEP   (NRAYS * C_CH)
#define OFF_W     (OFF_DEP + NRAYS)
#define OFF_WT    (OFF_W + NRAYS * SM1)

__global__ __launch_bounds__(256) void raymarch_kernel(
    const float* __restrict__ colors,     // [NRAYS, S, C]
    const float* __restrict__ densities,  // [NRAYS, S]
    const float* __restrict__ depths,     // [NRAYS, S]
    float* __restrict__ out)
{
    const int tid = blockIdx.x * blockDim.x + threadIdx.x;
    const int ray = tid >> 4;        // 16 threads per ray
    const int cq  = tid & 15;        // channel pair index: channels 2*cq, 2*cq+1
    if (ray >= NRAYS) return;

    const float2* __restrict__ col2 =
        reinterpret_cast<const float2*>(colors) + (size_t)ray * S_SAMP * (C_CH / 2) + cq;
    const float* __restrict__ den = densities + (size_t)ray * S_SAMP;
    const float* __restrict__ dep = depths    + (size_t)ray * S_SAMP;

    float* __restrict__ w_out = out + OFF_W + (size_t)ray * SM1;

    // previous-sample registers
    float2 cp = col2[0];
    float  dp = den[0];
    float  zp = dep[0];

    float T = 1.0f;            // exclusive transmittance
    float wt = 0.0f;           // weight_total
    float dacc = 0.0f;         // sum w * depth_mid
    float ax = 0.0f, ay = 0.0f;// sum w * color_mid (2 channels)

    #pragma unroll 4
    for (int s = 1; s < S_SAMP; ++s) {
        const float2 c = col2[(size_t)s * (C_CH / 2)];
        const float  d = den[s];
        const float  z = dep[s];

        const float delta = z - zp;
        const float dmid  = 0.5f * (d + dp) - 1.0f;
        // stable softplus
        const float sp    = fmaxf(dmid, 0.0f) + log1pf(expf(-fabsf(dmid)));
        const float alpha = 1.0f - expf(-sp * delta);
        const float w     = alpha * T;
        T *= (1.0f - alpha + 1e-10f);

        ax   += w * 0.5f * (c.x + cp.x);
        ay   += w * 0.5f * (c.y + cp.y);
        wt   += w;
        dacc += w * 0.5f * (z + zp);

        if (cq == 0) w_out[s - 1] = w;

        cp = c; dp = d; zp = z;
    }

    // composite_rgb = acc * 2 - 1
    float* __restrict__ rgb = out + OFF_RGB + (size_t)ray * C_CH + 2 * cq;
    rgb[0] = ax * 2.0f - 1.0f;
    rgb[1] = ay * 2.0f - 1.0f;

    if (cq == 0) {
        out[OFF_DEP + ray] = dacc / (wt + 0.001f);
        out[OFF_WT  + ray] = wt;
    }
}

extern "C" void kernel_launch(void* const* d_in, const int* in_sizes, int n_in,
                              void* d_out, int out_size, void* d_ws, size_t ws_size,
                              hipStream_t stream) {
    const float* colors    = (const float*)d_in[0];
    const float* densities = (const float*)d_in[1];
    const float* depths    = (const float*)d_in[2];
    float* out = (float*)d_out;

    const int total_threads = NRAYS * LPR;      // 262144
    const int block = 256;
    const int grid  = total_threads / block;    // 1024
    raymarch_kernel<<<grid, block, 0, stream>>>(colors, densities, depths, out);
}

// Round 2
// 27.352 us; speedup vs baseline: 2.2135x; 2.2135x over previous
//
#include <hip/hip_runtime.h>
#include <math.h>

// Problem constants: B=4, R=4096, S=48, C=32
#define NRAYS   (4 * 4096)   // 16384
#define S_SAMP  48
#define C_CH    32
#define SM1     (S_SAMP - 1) // 47

// Output flat layout (floats):
//   composite_rgb   [NRAYS * C_CH]  at 0
//   composite_depth [NRAYS]         at NRAYS*C_CH
//   weights         [NRAYS * SM1]
//   weight_total    [NRAYS]
#define OFF_RGB   0
#define OFF_DEP   (NRAYS * C_CH)
#define OFF_W     (OFF_DEP + NRAYS)
#define OFF_WT    (OFF_W + NRAYS * SM1)

// ---------------------------------------------------------------------------
// Kernel 1: per-ray serial scan (softplus -> alpha -> transmittance -> weights)
// Reads only densities+depths (6 MB). One thread per ray, fast-math
// transcendentals, fully unrolled with float4 input staging.
// ---------------------------------------------------------------------------
__global__ __launch_bounds__(64) void scan_kernel(
    const float* __restrict__ densities,  // [NRAYS, S]
    const float* __restrict__ depths,     // [NRAYS, S]
    float* __restrict__ out)
{
    const int ray = blockIdx.x * 64 + threadIdx.x;
    if (ray >= NRAYS) return;

    // stage 48 densities + 48 depths via float4 loads (192 B per ray, aligned)
    float4 dv[12], zv[12];
    const float4* __restrict__ d4 =
        reinterpret_cast<const float4*>(densities + (size_t)ray * S_SAMP);
    const float4* __restrict__ z4 =
        reinterpret_cast<const float4*>(depths + (size_t)ray * S_SAMP);
    #pragma unroll
    for (int i = 0; i < 12; ++i) { dv[i] = d4[i]; zv[i] = z4[i]; }
    const float* d = reinterpret_cast<const float*>(dv);
    const float* z = reinterpret_cast<const float*>(zv);

    float* __restrict__ w_out = out + OFF_W + (size_t)ray * SM1;

    float T = 1.0f, wt = 0.0f, dacc = 0.0f;
    #pragma unroll
    for (int s = 1; s < S_SAMP; ++s) {
        const float delta = z[s] - z[s - 1];
        const float dmid  = 0.5f * (d[s] + d[s - 1]) - 1.0f;
        // softplus(dmid), fast + stable: max(x,0) + log(1 + exp(-|x|))
        const float t     = __expf(-fabsf(dmid));
        const float sp    = fmaxf(dmid, 0.0f) + __logf(1.0f + t);
        const float alpha = 1.0f - __expf(-sp * delta);
        const float w     = alpha * T;
        T *= (1.0f - alpha + 1e-10f);

        w_out[s - 1] = w;
        wt   += w;
        dacc += w * 0.5f * (z[s] + z[s - 1]);
    }

    out[OFF_DEP + ray] = dacc / (wt + 0.001f);
    out[OFF_WT  + ray] = wt;
}

// ---------------------------------------------------------------------------
// Kernel 2: color composite — pure streaming, no transcendentals.
// 16 lanes per ray, each lane owns a float2 channel pair.
// composite_rgb = 2 * sum_s w_s * 0.5*(c_s + c_{s+1}) - 1
//               = sum_s w_s * (c_s + c_{s+1}) - 1
// ---------------------------------------------------------------------------
__global__ __launch_bounds__(256) void comp_kernel(
    const float* __restrict__ colors,   // [NRAYS, S, C]
    float* __restrict__ out)
{
    const int tid = blockIdx.x * 256 + threadIdx.x;
    const int ray = tid >> 4;
    const int cq  = tid & 15;

    const float2* __restrict__ col2 =
        reinterpret_cast<const float2*>(colors) + (size_t)ray * S_SAMP * (C_CH / 2) + cq;
    const float* __restrict__ w = out + OFF_W + (size_t)ray * SM1;

    float2 cp = col2[0];
    float ax = 0.0f, ay = 0.0f;

    #pragma unroll 8
    for (int s = 1; s < S_SAMP; ++s) {
        const float2 c  = col2[(size_t)s * (C_CH / 2)];
        const float  wv = w[s - 1];
        ax += wv * (c.x + cp.x);
        ay += wv * (c.y + cp.y);
        cp = c;
    }

    float* __restrict__ rgb = out + OFF_RGB + (size_t)ray * C_CH + 2 * cq;
    rgb[0] = ax - 1.0f;
    rgb[1] = ay - 1.0f;
}

extern "C" void kernel_launch(void* const* d_in, const int* in_sizes, int n_in,
                              void* d_out, int out_size, void* d_ws, size_t ws_size,
                              hipStream_t stream) {
    const float* colors    = (const float*)d_in[0];
    const float* densities = (const float*)d_in[1];
    const float* depths    = (const float*)d_in[2];
    float* out = (float*)d_out;

    // K1: one thread per ray, spread across all 256 CUs
    scan_kernel<<<NRAYS / 64, 64, 0, stream>>>(densities, depths, out);
    // K2: 16 lanes per ray (reads weights written by K1; same stream => ordered)
    comp_kernel<<<(NRAYS * 16) / 256, 256, 0, stream>>>(colors, out);
}